// Round 1
// baseline (272.748 us; speedup 1.0000x reference)
//
#include <hip/hip_runtime.h>

#define N_ROWS 8192
#define D_IN 1024
#define D_OUT 4096
#define NGROUPS 8

typedef unsigned short ushort_t;
typedef __attribute__((ext_vector_type(8))) __bf16 bf16x8;
typedef __attribute__((ext_vector_type(4))) float f32x4;

// ctl int-index layout in ws:
//  [0..7]   counts
//  [8..16]  offsets
//  [20..27] cursors
//  [28]     num_tiles
//  [32..]   tiles (int4: g, start, rows, pad), up to 120 tiles
//  [512..]  sorted row ids (8192)
#define CTL_NT 28
#define CTL_TILES 32
#define CTL_SORTED 512

__device__ __forceinline__ unsigned short f2bf(float f) {
  union { float f; unsigned u; } v; v.f = f;
  unsigned r = v.u + 0x7FFFu + ((v.u >> 16) & 1u);
  return (unsigned short)(r >> 16);
}

__device__ __forceinline__ void gload_lds16(const void* g, void* l) {
  __builtin_amdgcn_global_load_lds(
      (const __attribute__((address_space(1))) void*)g,
      (__attribute__((address_space(3))) void*)l, 16, 0, 0);
}

__global__ void k_zero(int* ctl) {
  if (threadIdx.x < 32) ctl[threadIdx.x] = 0;
}

__global__ void k_count(const int* __restrict__ gi, int* __restrict__ ctl) {
  __shared__ int c[NGROUPS];
  int i = blockIdx.x * 256 + threadIdx.x;
  if (threadIdx.x < NGROUPS) c[threadIdx.x] = 0;
  __syncthreads();
  if (i < N_ROWS) atomicAdd(&c[gi[i]], 1);
  __syncthreads();
  if (threadIdx.x < NGROUPS && c[threadIdx.x] != 0)
    atomicAdd(&ctl[threadIdx.x], c[threadIdx.x]);
}

__global__ void k_prefix(int* ctl) {
  if (threadIdx.x != 0 || blockIdx.x != 0) return;
  int* offs = ctl + 8;
  int* cur = ctl + 20;
  int* tiles = ctl + CTL_TILES;
  int off = 0, T = 0;
  for (int g = 0; g < NGROUPS; ++g) {
    offs[g] = off;
    cur[g] = off;
    int cnt = ctl[g];
    for (int m0 = 0; m0 < cnt; m0 += 128) {
      tiles[T * 4 + 0] = g;
      tiles[T * 4 + 1] = off + m0;
      tiles[T * 4 + 2] = min(128, cnt - m0);
      tiles[T * 4 + 3] = 0;
      ++T;
    }
    off += cnt;
  }
  offs[8] = off;
  ctl[CTL_NT] = T;
}

__global__ void k_scatter(const int* __restrict__ gi, int* __restrict__ ctl,
                          int* __restrict__ sorted) {
  int i = blockIdx.x * 256 + threadIdx.x;
  if (i < N_ROWS) {
    int g = gi[i];
    int pos = atomicAdd(&ctl[20 + g], 1);
    sorted[pos] = i;
  }
}

__global__ void k_convA(const float* __restrict__ A, ushort_t* __restrict__ Ab) {
  size_t i = ((size_t)blockIdx.x * 256 + threadIdx.x) * 4;
  float4 v = *reinterpret_cast<const float4*>(A + i);
  ushort4 o;
  o.x = f2bf(v.x); o.y = f2bf(v.y); o.z = f2bf(v.z); o.w = f2bf(v.w);
  *reinterpret_cast<ushort4*>(Ab + i) = o;
}

// W [g][k][n] f32 -> Wt [g][n][k] bf16 (64k x 32n tiles via LDS)
__global__ void k_transW(const float* __restrict__ W, ushort_t* __restrict__ Wt) {
  __shared__ float tile[64][33];
  int g = blockIdx.z;
  int n0 = blockIdx.x * 32;
  int k0 = blockIdx.y * 64;
  int t = threadIdx.x;
  int rn = t & 31, rk = t >> 5;
#pragma unroll
  for (int i = 0; i < 8; ++i) {
    int k = rk + i * 8;
    tile[k][rn] = W[((size_t)g * D_IN + k0 + k) * D_OUT + n0 + rn];
  }
  __syncthreads();
  int wk = t & 63, wnn = t >> 6;
#pragma unroll
  for (int i = 0; i < 8; ++i) {
    int n = wnn + i * 4;
    Wt[((size_t)g * D_OUT + n0 + n) * D_IN + k0 + wk] = f2bf(tile[wk][n]);
  }
}

// Grouped GEMM: 128x128 tile, BK=64, 4 waves (each 64x64), mfma_f32_16x16x32_bf16.
// LDS layout [k8][dim][8] bf16 -> conflict-free ds_read_b128, linear for global_load_lds.
__global__ __launch_bounds__(256) void k_gemm(
    const ushort_t* __restrict__ Ab, const ushort_t* __restrict__ Wt,
    const int* __restrict__ ctl, const int* __restrict__ sorted,
    const float* __restrict__ bias, float* __restrict__ out) {
  int tI = blockIdx.y;
  if (tI >= ctl[CTL_NT]) return;
  const int4 tl = reinterpret_cast<const int4*>(ctl + CTL_TILES)[tI];
  const int g = tl.x, start = tl.y, rows = tl.z;
  const int n_base = blockIdx.x * 128;

  __shared__ ushort_t Asm[8 * 128 * 8];  // 16 KB
  __shared__ ushort_t Bsm[8 * 128 * 8];  // 16 KB
  __shared__ int rowid[128];

  const int t = threadIdx.x;
  if (t < 128) {
    int idx = (t < rows) ? (start + t) : start;
    rowid[t] = sorted[idx];
  }
  __syncthreads();

  const ushort_t* agp[4];
  const ushort_t* bgp[4];
  ushort_t* ald[4];
  ushort_t* bld[4];
#pragma unroll
  for (int j = 0; j < 4; ++j) {
    int c = j * 256 + t;
    agp[j] = Ab + (size_t)rowid[c & 127] * D_IN + (c >> 7) * 8;
    bgp[j] = Wt + ((size_t)g * D_OUT + n_base + (c & 127)) * D_IN + (c >> 7) * 8;
    int ub = (j * 256 + (t & ~63)) * 8;
    ald[j] = Asm + ub;
    bld[j] = Bsm + ub;
  }

  const int lane = t & 63;
  const int w = t >> 6;
  const int wm = (w >> 1) * 64;
  const int wn = (w & 1) * 64;
  const int fr = lane & 15;
  const int fk = lane >> 4;

  f32x4 acc[4][4];
#pragma unroll
  for (int a = 0; a < 4; ++a)
#pragma unroll
    for (int b = 0; b < 4; ++b)
      acc[a][b] = (f32x4){0.f, 0.f, 0.f, 0.f};

  for (int k0 = 0; k0 < D_IN; k0 += 64) {
#pragma unroll
    for (int j = 0; j < 4; ++j) gload_lds16(agp[j] + k0, ald[j]);
#pragma unroll
    for (int j = 0; j < 4; ++j) gload_lds16(bgp[j] + k0, bld[j]);
    __syncthreads();
#pragma unroll
    for (int kk8 = 0; kk8 < 8; kk8 += 4) {
      bf16x8 a[4], b[4];
#pragma unroll
      for (int mb = 0; mb < 4; ++mb)
        a[mb] = *reinterpret_cast<const bf16x8*>(
            Asm + (((kk8 + fk) * 128) + wm + mb * 16 + fr) * 8);
#pragma unroll
      for (int nb = 0; nb < 4; ++nb)
        b[nb] = *reinterpret_cast<const bf16x8*>(
            Bsm + (((kk8 + fk) * 128) + wn + nb * 16 + fr) * 8);
#pragma unroll
      for (int mb = 0; mb < 4; ++mb)
#pragma unroll
        for (int nb = 0; nb < 4; ++nb)
          acc[mb][nb] = __builtin_amdgcn_mfma_f32_16x16x32_bf16(
              a[mb], b[nb], acc[mb][nb], 0, 0, 0);
    }
    __syncthreads();
  }

#pragma unroll
  for (int mb = 0; mb < 4; ++mb) {
#pragma unroll
    for (int r = 0; r < 4; ++r) {
      int m = wm + mb * 16 + fk * 4 + r;
      if (m < rows) {
        size_t ro = (size_t)rowid[m] * D_OUT;
#pragma unroll
        for (int nb = 0; nb < 4; ++nb) {
          int col = n_base + wn + nb * 16 + fr;
          out[ro + col] = acc[mb][nb][r] + bias[g * D_OUT + col];
        }
      }
    }
  }
}

// Fallback if workspace is too small: naive fp32 (correct, slow).
__global__ void k_naive(const float* __restrict__ A, const int* __restrict__ gi,
                        const float* __restrict__ W, const float* __restrict__ B,
                        float* __restrict__ out) {
  int row = blockIdx.x;
  int n = blockIdx.y * 256 + threadIdx.x;
  int g = gi[row];
  float s = B[(size_t)g * D_OUT + n];
  const float* wp = W + (size_t)g * D_IN * D_OUT + n;
  const float* a = A + (size_t)row * D_IN;
  for (int k = 0; k < D_IN; ++k) s += a[k] * wp[(size_t)k * D_OUT];
  out[(size_t)row * D_OUT + n] = s;
}

extern "C" void kernel_launch(void* const* d_in, const int* in_sizes, int n_in,
                              void* d_out, int out_size, void* d_ws, size_t ws_size,
                              hipStream_t stream) {
  const float* A = (const float*)d_in[0];
  const int* gi = (const int*)d_in[1];
  const float* W = (const float*)d_in[2];
  const float* B = (const float*)d_in[3];
  float* out = (float*)d_out;

  const size_t A_OFF = 65536;
  const size_t W_OFF = A_OFF + (size_t)N_ROWS * D_IN * 2;
  const size_t NEED = W_OFF + (size_t)NGROUPS * D_IN * D_OUT * 2;

  if (ws_size < NEED) {
    dim3 grid(N_ROWS, D_OUT / 256);
    k_naive<<<grid, dim3(256), 0, stream>>>(A, gi, W, B, out);
    return;
  }

  int* ctl = (int*)d_ws;
  int* sorted = ctl + CTL_SORTED;
  ushort_t* Ab = (ushort_t*)((char*)d_ws + A_OFF);
  ushort_t* Wt = (ushort_t*)((char*)d_ws + W_OFF);

  k_zero<<<1, 32, 0, stream>>>(ctl);
  k_count<<<N_ROWS / 256, 256, 0, stream>>>(gi, ctl);
  k_prefix<<<1, 64, 0, stream>>>(ctl);
  k_scatter<<<N_ROWS / 256, 256, 0, stream>>>(gi, ctl, sorted);
  k_convA<<<(N_ROWS * D_IN / 4) / 256, 256, 0, stream>>>(A, Ab);
  dim3 tg(D_OUT / 32, D_IN / 64, NGROUPS);
  k_transW<<<tg, 256, 0, stream>>>(W, Wt);
  dim3 gg(D_OUT / 128, 72);
  k_gemm<<<gg, 256, 0, stream>>>(Ab, Wt, ctl, sorted, B, out);
}